// Round 4
// baseline (948.086 us; speedup 1.0000x reference)
//
#include <hip/hip_runtime.h>

#define N_NODES 100000
#define N_EDGES 1600000
#define DIM 128
#define N_RATES 5
#define OUT_W (N_RATES * DIM)          // 640
#define PK_SHIFT 17                     // src < 2^17, rate in bits 17..19
#define PK_MASK  0x1FFFF
#define SCAN_NB ((N_NODES + 1023) / 1024)   // 98

// ---- workspace layout (bytes) ----
#define WS_DEG_OUT 0x000000u   // int[5N]  2 MB
#define WS_DEG_IN  0x200000u   // int[5N]  2 MB
#define WS_NSRC    0x400000u   // f32[5N]  2 MB
#define WS_NDST    0x600000u   // f32[5N]  2 MB
#define WS_OFFS    0x800000u   // int[N]   400 KB
#define WS_CURSOR  0x880000u   // int[N]   400 KB
#define WS_BSUM    0x900000u   // int[98]
#define WS_PACKED  0xA00000u   // int[E]   6.4 MB (ends 0x101A800)
#define WS_G       0x1100000u  // f32 G' slots, 51.2 MB each
#define SLOT_BYTES ((size_t)N_NODES * DIM * sizeof(float))

// ---------------------------------------------------------------------------
// Per-(rate,node) degree histograms (int atomics into zeroed ws).
// ---------------------------------------------------------------------------
__global__ __launch_bounds__(256) void deg_kernel(const int* __restrict__ src,
                                                  const int* __restrict__ dst,
                                                  const int* __restrict__ rate,
                                                  int* __restrict__ deg_out,
                                                  int* __restrict__ deg_in) {
    int e = blockIdx.x * 256 + threadIdx.x;
    if (e >= N_EDGES) return;
    int r = rate[e];
    atomicAdd(&deg_out[r * N_NODES + src[e]], 1);
    atomicAdd(&deg_in [r * N_NODES + dst[e]], 1);
}

// ---------------------------------------------------------------------------
// norm = max(deg,1)^-0.5 for all (rate,node).
// ---------------------------------------------------------------------------
__global__ __launch_bounds__(256) void norm_kernel(const int* __restrict__ deg_out,
                                                   const int* __restrict__ deg_in,
                                                   float* __restrict__ nsrc,
                                                   float* __restrict__ ndst) {
    int i = blockIdx.x * 256 + threadIdx.x;
    if (i >= N_RATES * N_NODES) return;
    int d0 = deg_out[i]; if (d0 < 1) d0 = 1;
    int d1 = deg_in[i];  if (d1 < 1) d1 = 1;
    nsrc[i] = 1.0f / sqrtf((float)d0);
    ndst[i] = 1.0f / sqrtf((float)d1);
}

// ---------------------------------------------------------------------------
// Exclusive scan of per-dst total in-degree (sum over 5 rate rows of deg_in).
// ---------------------------------------------------------------------------
__global__ __launch_bounds__(256) void scan1_kernel(const int* __restrict__ deg_in,
                                                    int* __restrict__ offs,
                                                    int* __restrict__ bsum) {
    __shared__ int sh[256];
    int tid = threadIdx.x;
    int base = blockIdx.x * 1024 + tid * 4;
    int v[4];
#pragma unroll
    for (int j = 0; j < 4; ++j) {
        int idx = base + j, s = 0;
        if (idx < N_NODES) {
#pragma unroll
            for (int r = 0; r < N_RATES; ++r) s += deg_in[r * N_NODES + idx];
        }
        v[j] = s;
    }
    int tsum = v[0] + v[1] + v[2] + v[3];
    sh[tid] = tsum;
    __syncthreads();
    for (int off = 1; off < 256; off <<= 1) {          // Hillis-Steele inclusive
        int t = (tid >= off) ? sh[tid - off] : 0;
        __syncthreads();
        sh[tid] += t;
        __syncthreads();
    }
    int excl = sh[tid] - tsum;
#pragma unroll
    for (int j = 0; j < 4; ++j) {
        int idx = base + j;
        if (idx < N_NODES) offs[idx] = excl;
        excl += v[j];
    }
    if (tid == 255) bsum[blockIdx.x] = sh[255];
}

__global__ void scan2_kernel(int* __restrict__ bsum) {
    if (threadIdx.x != 0 || blockIdx.x != 0) return;
    int run = 0;
    for (int i = 0; i < SCAN_NB; ++i) { int t = bsum[i]; bsum[i] = run; run += t; }
}

__global__ __launch_bounds__(256) void scan3_kernel(int* __restrict__ offs,
                                                    const int* __restrict__ bsum,
                                                    int* __restrict__ cursor) {
    int i = blockIdx.x * 256 + threadIdx.x;
    if (i >= N_NODES) return;
    int v = offs[i] + bsum[i >> 10];
    offs[i] = v;
    cursor[i] = v;
}

// ---------------------------------------------------------------------------
// CSR fill: packed[pos] = src | (rate<<17), bucketed by dst via atomic cursor.
// ---------------------------------------------------------------------------
__global__ __launch_bounds__(256) void fill_kernel(const int* __restrict__ src,
                                                   const int* __restrict__ dst,
                                                   const int* __restrict__ rate,
                                                   int* __restrict__ cursor,
                                                   int* __restrict__ packed) {
    int e = blockIdx.x * 256 + threadIdx.x;
    if (e >= N_EDGES) return;
    int pos = atomicAdd(&cursor[dst[e]], 1);
    packed[pos] = src[e] | (rate[e] << PK_SHIFT);
}

// ---------------------------------------------------------------------------
// G'[slot][n] = (h[n] @ W[rbase+slot]) * nsrc[rbase+slot][n]  (dense GEMM)
// 64x128 tile, TK=32, f32 vector FMA; blockIdx.y = slot within group.
// ---------------------------------------------------------------------------
__global__ __launch_bounds__(256) void gemm_g_kernel(const float* __restrict__ h,
                                                     const float* __restrict__ Wall,
                                                     const float* __restrict__ nsrc,
                                                     float* __restrict__ G,
                                                     int rbase) {
    __shared__ float sW[32][128];   // [k][c] 16 KB
    __shared__ float sA[32][64];    // [k][row] 8 KB (transposed for b128 bcast)
    int slot = blockIdx.y;
    int r = rbase + slot;
    const float* W  = Wall + (size_t)r * DIM * DIM;
    const float* ns = nsrc + (size_t)r * N_NODES;
    int tid  = threadIdx.x;
    int row0 = blockIdx.x * 64;
    int c2   = (tid & 63) * 2;
    int rg   = tid >> 6;
    int rb   = rg * 16;

    float acc0[16], acc1[16];
#pragma unroll
    for (int i = 0; i < 16; ++i) { acc0[i] = 0.f; acc1[i] = 0.f; }

    for (int kc = 0; kc < 128; kc += 32) {
        __syncthreads();
#pragma unroll
        for (int j = 0; j < 4; ++j) {
            int f = tid * 4 + j * 1024;
            int kl = f >> 7, c = f & 127;
            *(float4*)(&sW[kl][c]) = *(const float4*)(W + (kc + kl) * 128 + c);
        }
#pragma unroll
        for (int j = 0; j < 2; ++j) {
            int f = tid * 4 + j * 1024;
            int rowl = f >> 5, kl = f & 31;
            int grow = row0 + rowl;
            float4 a4 = make_float4(0.f, 0.f, 0.f, 0.f);
            if (grow < N_NODES) a4 = *(const float4*)(h + (size_t)grow * DIM + kc + kl);
            sA[kl + 0][rowl] = a4.x; sA[kl + 1][rowl] = a4.y;
            sA[kl + 2][rowl] = a4.z; sA[kl + 3][rowl] = a4.w;
        }
        __syncthreads();
#pragma unroll
        for (int k = 0; k < 32; ++k) {
            float2 w = *(const float2*)(&sW[k][c2]);
#pragma unroll
            for (int i = 0; i < 4; ++i) {
                float4 a = *(const float4*)(&sA[k][rb + i * 4]);
                acc0[i*4+0] += a.x * w.x; acc1[i*4+0] += a.x * w.y;
                acc0[i*4+1] += a.y * w.x; acc1[i*4+1] += a.y * w.y;
                acc0[i*4+2] += a.z * w.x; acc1[i*4+2] += a.z * w.y;
                acc0[i*4+3] += a.w * w.x; acc1[i*4+3] += a.w * w.y;
            }
        }
    }
#pragma unroll
    for (int i = 0; i < 16; ++i) {
        int row = row0 + rb + i;
        if (row < N_NODES) {
            float nsv = ns[row];
            float2 o; o.x = acc0[i] * nsv; o.y = acc1[i] * nsv;
            *(float2*)(G + ((size_t)slot * N_NODES + row) * DIM + c2) = o;
        }
    }
}

// ---------------------------------------------------------------------------
// Gather: one wave per dst; unroll-4 (load phase split from accumulate phase
// so 4 G-row loads are in flight). Rates outside [rbase, rbase+GS) skipped via
// wave-uniform branches (ALL=true removes the checks for the 1-group case).
// Out blocks for this group's rates written exactly once; bias+norm fused.
// ---------------------------------------------------------------------------
template<int GS, bool ALL>
__global__ __launch_bounds__(256) void gather_kernel(const float* __restrict__ G,
                                                     const int* __restrict__ packed,
                                                     const int* __restrict__ offs,
                                                     const float* __restrict__ ndst,
                                                     const float* __restrict__ bias,
                                                     float* __restrict__ out,
                                                     int rbase) {
    int gw   = (blockIdx.x * 256 + threadIdx.x) >> 6;  // wave id == dst
    int lane = threadIdx.x & 63;
    if (gw >= N_NODES) return;
    int d = gw;
    int beg = offs[d];
    int end = (d == N_NODES - 1) ? N_EDGES : offs[d + 1];

    float2 a0 = make_float2(0.f, 0.f), a1 = a0, a2 = a0, a3 = a0, a4 = a0;

    int p = beg;
    for (; p + 4 <= end; p += 4) {
        int pk[4]; int rl[4]; bool use[4]; float2 v[4];
#pragma unroll
        for (int i = 0; i < 4; ++i) pk[i] = packed[p + i];
#pragma unroll
        for (int i = 0; i < 4; ++i) {
            rl[i]  = (pk[i] >> PK_SHIFT) - rbase;
            use[i] = ALL || ((unsigned)rl[i] < (unsigned)GS);
        }
#pragma unroll
        for (int i = 0; i < 4; ++i) {
            int s = pk[i] & PK_MASK;
            if (use[i])
                v[i] = *(const float2*)(G + ((size_t)rl[i] * N_NODES + s) * DIM + lane * 2);
        }
#pragma unroll
        for (int i = 0; i < 4; ++i) {
            if (!use[i]) continue;
            switch (rl[i]) {
                case 0: a0.x += v[i].x; a0.y += v[i].y; break;
                case 1: if constexpr (GS > 1) { a1.x += v[i].x; a1.y += v[i].y; } break;
                case 2: if constexpr (GS > 2) { a2.x += v[i].x; a2.y += v[i].y; } break;
                case 3: if constexpr (GS > 3) { a3.x += v[i].x; a3.y += v[i].y; } break;
                default: if constexpr (GS > 4) { a4.x += v[i].x; a4.y += v[i].y; } break;
            }
        }
    }
    for (; p < end; ++p) {
        int pkx = packed[p];
        int rlx = (pkx >> PK_SHIFT) - rbase;
        if (!ALL && (unsigned)rlx >= (unsigned)GS) continue;
        int s = pkx & PK_MASK;
        float2 v = *(const float2*)(G + ((size_t)rlx * N_NODES + s) * DIM + lane * 2);
        switch (rlx) {
            case 0: a0.x += v.x; a0.y += v.y; break;
            case 1: if constexpr (GS > 1) { a1.x += v.x; a1.y += v.y; } break;
            case 2: if constexpr (GS > 2) { a2.x += v.x; a2.y += v.y; } break;
            case 3: if constexpr (GS > 3) { a3.x += v.x; a3.y += v.y; } break;
            default: if constexpr (GS > 4) { a4.x += v.x; a4.y += v.y; } break;
        }
    }

    float* orow = out + (size_t)d * OUT_W + lane * 2;
#pragma unroll
    for (int ri = 0; ri < GS; ++ri) {
        int r = rbase + ri;
        float ndv = ndst[(size_t)r * N_NODES + d];
        float2 bb = *(const float2*)(bias + r * DIM + lane * 2);
        float2 acc = (ri == 0) ? a0 : (ri == 1) ? a1 : (ri == 2) ? a2
                   : (ri == 3) ? a3 : a4;
        float2 o; o.x = acc.x * ndv + bb.x; o.y = acc.y * ndv + bb.y;
        *(float2*)(orow + r * DIM) = o;
    }
}

// ===========================================================================
// Minimal-ws fallback (needs only 8 MB): scatter h*ns into out (atomics),
// then in-place per-tile GEMM with norm+bias epilogue.
// ===========================================================================
__global__ __launch_bounds__(256) void zero_out_kernel(float4* __restrict__ out) {
    int i = blockIdx.x * 256 + threadIdx.x;
    if (i < N_NODES * OUT_W / 4) out[i] = make_float4(0.f, 0.f, 0.f, 0.f);
}

__global__ __launch_bounds__(256) void scatter_c_kernel(const float* __restrict__ h,
                                                        const int* __restrict__ src,
                                                        const int* __restrict__ dst,
                                                        const int* __restrict__ rate,
                                                        const float* __restrict__ nsrc,
                                                        float* __restrict__ out) {
    int lane = threadIdx.x & 63;
    int gw = (blockIdx.x * 256 + threadIdx.x) >> 6;
    int e0 = gw * 4;
#pragma unroll
    for (int i = 0; i < 4; ++i) {
        int e = e0 + i;
        if (e >= N_EDGES) return;
        int s = src[e], d = dst[e], r = rate[e];
        float ns = nsrc[(size_t)r * N_NODES + s];
        float2 v = *(const float2*)(h + (size_t)s * DIM + lane * 2);
        float* o = out + (size_t)d * OUT_W + r * DIM + lane * 2;
        unsafeAtomicAdd(o,     v.x * ns);
        unsafeAtomicAdd(o + 1, v.y * ns);
    }
}

__global__ __launch_bounds__(256) void gemm_inplace_kernel(float* __restrict__ outp,
                                                           const float* __restrict__ Wall,
                                                           const float* __restrict__ bias,
                                                           const float* __restrict__ ndst,
                                                           int r) {
    __shared__ float sW[32][128];
    __shared__ float sA[32][64];
    float* A = outp + r * DIM;                       // lda = OUT_W, in-place
    const float* Wr = Wall + (size_t)r * DIM * DIM;
    const float* nd = ndst + (size_t)r * N_NODES;
    const float* br = bias + (size_t)r * DIM;
    int tid  = threadIdx.x;
    int row0 = blockIdx.x * 64;
    int c2   = (tid & 63) * 2;
    int rg   = tid >> 6;
    int rb   = rg * 16;
    float acc0[16], acc1[16];
#pragma unroll
    for (int i = 0; i < 16; ++i) { acc0[i] = 0.f; acc1[i] = 0.f; }
    for (int kc = 0; kc < 128; kc += 32) {
        __syncthreads();
#pragma unroll
        for (int j = 0; j < 4; ++j) {
            int f = tid * 4 + j * 1024;
            int kl = f >> 7, c = f & 127;
            *(float4*)(&sW[kl][c]) = *(const float4*)(Wr + (kc + kl) * 128 + c);
        }
#pragma unroll
        for (int j = 0; j < 2; ++j) {
            int f = tid * 4 + j * 1024;
            int rowl = f >> 5, kl = f & 31;
            int grow = row0 + rowl;
            float4 a4 = make_float4(0.f, 0.f, 0.f, 0.f);
            if (grow < N_NODES) a4 = *(const float4*)(A + (size_t)grow * OUT_W + kc + kl);
            sA[kl + 0][rowl] = a4.x; sA[kl + 1][rowl] = a4.y;
            sA[kl + 2][rowl] = a4.z; sA[kl + 3][rowl] = a4.w;
        }
        __syncthreads();
#pragma unroll
        for (int k = 0; k < 32; ++k) {
            float2 w = *(const float2*)(&sW[k][c2]);
#pragma unroll
            for (int i = 0; i < 4; ++i) {
                float4 a = *(const float4*)(&sA[k][rb + i * 4]);
                acc0[i*4+0] += a.x * w.x; acc1[i*4+0] += a.x * w.y;
                acc0[i*4+1] += a.y * w.x; acc1[i*4+1] += a.y * w.y;
                acc0[i*4+2] += a.z * w.x; acc1[i*4+2] += a.z * w.y;
                acc0[i*4+3] += a.w * w.x; acc1[i*4+3] += a.w * w.y;
            }
        }
    }
#pragma unroll
    for (int i = 0; i < 16; ++i) {
        int row = row0 + rb + i;
        if (row < N_NODES) {
            float ndv = nd[row];
            float2 o;
            o.x = acc0[i] * ndv + br[c2];
            o.y = acc1[i] * ndv + br[c2 + 1];
            *(float2*)(A + (size_t)row * OUT_W + c2) = o;
        }
    }
}

// ---------------------------------------------------------------------------
extern "C" void kernel_launch(void* const* d_in, const int* in_sizes, int n_in,
                              void* d_out, int out_size, void* d_ws, size_t ws_size,
                              hipStream_t stream) {
    const float* h    = (const float*)d_in[0];   // [N,128]
    const float* W    = (const float*)d_in[1];   // [5,128,128]
    const float* b    = (const float*)d_in[2];   // [5,128]
    const int*   src  = (const int*)d_in[3];     // int32 per harness contract
    const int*   dst  = (const int*)d_in[4];
    const int*   rate = (const int*)d_in[5];
    float* out = (float*)d_out;                  // [N, 640]

    char* ws = (char*)d_ws;
    int*   deg_out = (int*)(ws + WS_DEG_OUT);
    int*   deg_in  = (int*)(ws + WS_DEG_IN);
    float* nsrc    = (float*)(ws + WS_NSRC);
    float* ndst    = (float*)(ws + WS_NDST);
    int*   offs    = (int*)(ws + WS_OFFS);
    int*   cursor  = (int*)(ws + WS_CURSOR);
    int*   bsum    = (int*)(ws + WS_BSUM);
    int*   packed  = (int*)(ws + WS_PACKED);
    float* G       = (float*)(ws + WS_G);

    int n_slots = 0;
    if (ws_size > WS_G) n_slots = (int)((ws_size - WS_G) / SLOT_BYTES);
    if (n_slots > N_RATES) n_slots = N_RATES;

    // degrees + norms (both paths)
    hipMemsetAsync(ws, 0, 0x400000, stream);
    deg_kernel<<<(N_EDGES + 255) / 256, 256, 0, stream>>>(src, dst, rate, deg_out, deg_in);
    norm_kernel<<<(N_RATES * N_NODES + 255) / 256, 256, 0, stream>>>(deg_out, deg_in,
                                                                     nsrc, ndst);

    if (n_slots >= 1) {
        // ---- CSR-gather path (no float atomics), rate-group tiled by ws ----
        scan1_kernel<<<SCAN_NB, 256, 0, stream>>>(deg_in, offs, bsum);
        scan2_kernel<<<1, 1, 0, stream>>>(bsum);
        scan3_kernel<<<(N_NODES + 255) / 256, 256, 0, stream>>>(offs, bsum, cursor);
        fill_kernel<<<(N_EDGES + 255) / 256, 256, 0, stream>>>(src, dst, rate,
                                                               cursor, packed);
        const int ggrid = (N_NODES * 64 + 255) / 256;   // one wave per dst
        int done = 0;
        while (done < N_RATES) {
            int gs = N_RATES - done; if (gs > n_slots) gs = n_slots;
            gemm_g_kernel<<<dim3((N_NODES + 63) / 64, gs), 256, 0, stream>>>(h, W, nsrc,
                                                                             G, done);
            switch (gs) {
                case 5: gather_kernel<5, true ><<<ggrid, 256, 0, stream>>>(G, packed, offs,
                                                                           ndst, b, out, done); break;
                case 4: gather_kernel<4, false><<<ggrid, 256, 0, stream>>>(G, packed, offs,
                                                                           ndst, b, out, done); break;
                case 3: gather_kernel<3, false><<<ggrid, 256, 0, stream>>>(G, packed, offs,
                                                                           ndst, b, out, done); break;
                case 2: gather_kernel<2, false><<<ggrid, 256, 0, stream>>>(G, packed, offs,
                                                                           ndst, b, out, done); break;
                default: gather_kernel<1, false><<<ggrid, 256, 0, stream>>>(G, packed, offs,
                                                                            ndst, b, out, done); break;
            }
            done += gs;
        }
    } else {
        // ---- minimal-ws fallback: atomic scatter into out + in-place GEMM ----
        zero_out_kernel<<<(N_NODES * OUT_W / 4 + 255) / 256, 256, 0, stream>>>((float4*)out);
        scatter_c_kernel<<<(N_EDGES / 4 * 64 + 255) / 256, 256, 0, stream>>>(h, src, dst,
                                                                             rate, nsrc, out);
        for (int r = 0; r < N_RATES; ++r)
            gemm_inplace_kernel<<<(N_NODES + 63) / 64, 256, 0, stream>>>(out, W, b, ndst, r);
    }
}